// Round 9
// baseline (2358.647 us; speedup 1.0000x reference)
//
#include <hip/hip_runtime.h>

#define NB 8
#define NN 8192
#define NC 32
#define NPOINT 1024
#define NSAMPLE 32

// Exact round-to-nearest distance, no fma contraction: matches numpy
// ((dx*dx + dy*dy) + dz*dz) bitwise.
__device__ __forceinline__ float d2_exact(float ax, float ay, float az,
                                          float bx, float by, float bz) {
    float dx = __fsub_rn(ax, bx);
    float dy = __fsub_rn(ay, by);
    float dz = __fsub_rn(az, bz);
    return __fadd_rn(__fadd_rn(__fmul_rn(dx, dx), __fmul_rn(dy, dy)),
                     __fmul_rn(dz, dz));
}

typedef float __attribute__((ext_vector_type(2))) f32x2;
typedef unsigned long long __attribute__((ext_vector_type(2))) u64x2;

__device__ __forceinline__ f32x2 pk_sub(f32x2 a, f32x2 b) {
    f32x2 d;
    asm("v_pk_add_f32 %0, %1, %2 neg_lo:[0,1] neg_hi:[0,1]"
        : "=v"(d) : "v"(a), "v"(b));
    return d;
}
__device__ __forceinline__ f32x2 pk_mul(f32x2 a, f32x2 b) {
    f32x2 d;
    asm("v_pk_mul_f32 %0, %1, %2" : "=v"(d) : "v"(a), "v"(b));
    return d;
}
__device__ __forceinline__ f32x2 pk_add(f32x2 a, f32x2 b) {
    f32x2 d;
    asm("v_pk_add_f32 %0, %1, %2" : "=v"(d) : "v"(a), "v"(b));
    return d;
}
// acc = a*b + acc (per-component fma). Used only in the MLP (threshold 8.4e-2).
__device__ __forceinline__ void pk_fma(f32x2& acc, f32x2 a, f32x2 b) {
    asm("v_pk_fma_f32 %0, %1, %2, %0" : "+v"(acc) : "v"(a), "v"(b));
}

// ---------------------------------------------------------------------------
// Kernel 1: FPS, one block/batch, 256 threads (4 waves, 1 wave/SIMD), K=32.
//
// Round 2-8 evidence: per-iter time is dominated by a config-invariant
// ~1700-2000 cyc SERIAL chain (barrier + LDS round trip + DPP chain + winner
// global load), not by issue count. This round attacks the serial chain:
//  - all coords staged in 96 KB dynamic LDS -> winner read = 3 broadcast
//    ds_read_b32 instead of a ~300-600 cyc random global scalar load;
//  - cross-wave slots read as 2x ds_read_b128 (alignas(16), 4 u64 slots);
//  - per-thread argmax as a depth-5 tree (latency ~40 cyc vs 128 serial).
// Key = (f32_bits(dist)<<32) | ~p : max == numpy argmax w/ first-occurrence.
// ---------------------------------------------------------------------------
#define FPS_T 256
#define FPS_K (NN / FPS_T)   // 32
#define FPS_J (FPS_K / 2)    // 16 pairs

__device__ __forceinline__ unsigned long long kmax64(unsigned long long a,
                                                     unsigned long long b) {
    return a > b ? a : b;
}

template <int CTRL, int RM>
__device__ __forceinline__ unsigned long long dpp_k(unsigned long long k) {
    unsigned hi = (unsigned)__builtin_amdgcn_update_dpp(
        0, (int)(k >> 32), CTRL, RM, 0xf, true);
    unsigned lo = (unsigned)__builtin_amdgcn_update_dpp(
        0, (int)(k & 0xffffffffULL), CTRL, RM, 0xf, true);
    return ((unsigned long long)hi << 32) | lo;
}

__global__ __launch_bounds__(FPS_T, 1) void fps_kernel(
    const float* __restrict__ xyz, const float* __restrict__ normal,
    float* __restrict__ out_xyz, float* __restrict__ out_normal) {
    extern __shared__ float sxyz[];   // 24576 floats = 96 KB, coords copy
    const int b = blockIdx.x;
    const float* bx = xyz + (size_t)b * NN * 3;
    const int tid = threadIdx.x;
    const int lane = tid & 63;
    const int wave = tid >> 6;   // 0..3

    __shared__ alignas(16) unsigned long long redk[2][4];
    __shared__ int sel_hist[NPOINT];

    // ---- stage coords into LDS (float4, 24 steps) -------------------------
    for (int j = tid * 4; j < NN * 3; j += FPS_T * 4) {
        float4 v = *(const float4*)(bx + j);
        *(float4*)(sxyz + j) = v;
    }

    // Pair layout: pair j = points p0 = tid + 2j*FPS_T (.x), p1 = p0+FPS_T (.y)
    f32x2 px2[FPS_J], py2[FPS_J], pz2[FPS_J];
    float dist[FPS_K];
#pragma unroll
    for (int j = 0; j < FPS_J; ++j) {
        int p0 = tid + (2 * j) * FPS_T;
        int p1 = tid + (2 * j + 1) * FPS_T;
        px2[j].x = bx[p0 * 3 + 0]; px2[j].y = bx[p1 * 3 + 0];
        py2[j].x = bx[p0 * 3 + 1]; py2[j].y = bx[p1 * 3 + 1];
        pz2[j].x = bx[p0 * 3 + 2]; pz2[j].y = bx[p1 * 3 + 2];
        dist[2 * j] = 1e10f;
        dist[2 * j + 1] = 1e10f;
    }
#pragma unroll
    for (int j = 0; j < FPS_J; ++j) {
        asm volatile("" : "+v"(px2[j]), "+v"(py2[j]), "+v"(pz2[j]));
    }
    __syncthreads();   // staging complete

    int p_prev = 0;
    float lx = bx[0], ly = bx[1], lz = bx[2];

    for (int it = 0; it < NPOINT; ++it) {
        const int par = it & 1;
        if (tid == 0) sel_hist[it] = p_prev;

        f32x2 lx2, ly2, lz2;
        lx2.x = lx; lx2.y = lx;
        ly2.x = ly; ly2.y = ly;
        lz2.x = lz; lz2.y = lz;

        // update + pairwise argmax (tie -> lower k kept by >= / strict >)
        float pv[FPS_J];
        int pi[FPS_J];
#pragma unroll
        for (int j = 0; j < FPS_J; ++j) {
            f32x2 dx = pk_sub(px2[j], lx2);
            f32x2 dy = pk_sub(py2[j], ly2);
            f32x2 dz = pk_sub(pz2[j], lz2);
            f32x2 s  = pk_add(pk_mul(dx, dx), pk_mul(dy, dy));
            f32x2 d  = pk_add(s, pk_mul(dz, dz));
            float nd0 = fminf(dist[2 * j], d.x);
            float nd1 = fminf(dist[2 * j + 1], d.y);
            dist[2 * j] = nd0;
            dist[2 * j + 1] = nd1;
            bool g = nd1 > nd0;            // strict >: tie keeps lower index
            pv[j] = g ? nd1 : nd0;
            pi[j] = g ? (2 * j + 1) : (2 * j);
        }
        // tree merge 16 -> 1 (left half has smaller indices; strict > keeps left)
#pragma unroll
        for (int w = 8; w >= 1; w >>= 1) {
#pragma unroll
            for (int j = 0; j < 8; ++j) {
                if (j < w) {
                    bool g = pv[j + w] > pv[j];
                    pv[j] = g ? pv[j + w] : pv[j];
                    pi[j] = g ? pi[j + w] : pi[j];
                }
            }
        }
        int bp = tid + (pi[0] << 8);       // global point index (FPS_T == 256)
        unsigned long long key =
            ((unsigned long long)__float_as_uint(pv[0]) << 32) |
            (unsigned)(~bp);

        // wave-wide max via DPP (zero-fill safe: key 0 never beats real keys)
        key = kmax64(key, dpp_k<0x111, 0xf>(key));
        key = kmax64(key, dpp_k<0x112, 0xf>(key));
        key = kmax64(key, dpp_k<0x114, 0xf>(key));
        key = kmax64(key, dpp_k<0x118, 0xf>(key));
        key = kmax64(key, dpp_k<0x142, 0xa>(key));
        key = kmax64(key, dpp_k<0x143, 0xc>(key));
        if (lane == 63) redk[par][wave] = key;
        __syncthreads();

        // cross-wave: 2x ds_read_b128 (4 slots) + kmax tree
        u64x2 a = *(const u64x2*)&redk[par][0];
        u64x2 c = *(const u64x2*)&redk[par][2];
        unsigned long long g = kmax64(kmax64(a.x, a.y), kmax64(c.x, c.y));
        int p = (int)(~(unsigned)(g & 0xffffffffULL));
        // winner coords from LDS (broadcast reads, ~150 cyc vs global ~400+)
        lx = sxyz[p * 3 + 0];
        ly = sxyz[p * 3 + 1];
        lz = sxyz[p * 3 + 2];
        p_prev = p;
    }
    __syncthreads();

    // gather new_xyz / new_normal (xyz from LDS copy: identical bits)
    const float* bn = normal + (size_t)b * NN * 3;
    for (int t = tid; t < NPOINT; t += FPS_T) {
        int i = sel_hist[t];
        size_t o = ((size_t)b * NPOINT + t) * 3;
        out_xyz[o + 0] = sxyz[i * 3 + 0];
        out_xyz[o + 1] = sxyz[i * 3 + 1];
        out_xyz[o + 2] = sxyz[i * 3 + 2];
        out_normal[o + 0] = bn[i * 3 + 0];
        out_normal[o + 1] = bn[i * 3 + 1];
        out_normal[o + 2] = bn[i * 3 + 2];
    }
}

// ---------------------------------------------------------------------------
// Kernel 2: ball query + gather + 3-layer MLP + maxpool, one wave/centroid,
// 2 waves per block. MLP inner products use v_pk_fma_f32 (2 channels/instr).
// ---------------------------------------------------------------------------
#define K2_WAVES 2
#define XS 37   // X row stride (35 cols + pad)
#define HS 65   // H row stride (64 cols + pad)

__global__ __launch_bounds__(64 * K2_WAVES) void group_mlp_kernel(
    const float* __restrict__ xyz, const float* __restrict__ features,
    const float* __restrict__ w1, const float* __restrict__ b1,
    const float* __restrict__ w2, const float* __restrict__ b2,
    const float* __restrict__ w3, const float* __restrict__ b3,
    const float* __restrict__ new_xyz, float* __restrict__ out_feat) {
    const int wave = threadIdx.x >> 6;
    const int lane = threadIdx.x & 63;
    const int g = blockIdx.x * K2_WAVES + wave;   // centroid id, 0..8191
    const int b = g >> 10;
    const int p = g & 1023;
    const float* bxp = xyz + (size_t)b * NN * 3;
    const float* bfp = features + (size_t)b * NN * NC;

    __shared__ int sel_s[K2_WAVES][NSAMPLE];
    __shared__ float bufA[K2_WAVES][32 * HS];
    __shared__ float bufB[K2_WAVES][32 * HS];

    const float cx = new_xyz[(size_t)g * 3 + 0];
    const float cy = new_xyz[(size_t)g * 3 + 1];
    const float cz = new_xyz[(size_t)g * 3 + 2];

    // ---- ball query: first NSAMPLE hits in ascending index order ----------
    int have = 0;
    for (int ch = 0; ch < NN / 64 && have < NSAMPLE; ++ch) {
        int j = ch * 64 + lane;
        float x = bxp[j * 3 + 0], y = bxp[j * 3 + 1], z = bxp[j * 3 + 2];
        float d2 = d2_exact(x, y, z, cx, cy, cz);
        bool hit = d2 < 0.04f;
        unsigned long long m = __ballot(hit);
        int pos = have + __popcll(m & ((1ull << lane) - 1ull));
        if (hit && pos < NSAMPLE) sel_s[wave][pos] = j;
        have += __popcll(m);
    }
    __syncthreads();
    int nsel = have < NSAMPLE ? have : NSAMPLE;
    int first = sel_s[wave][0];
    if (lane < NSAMPLE && lane >= nsel) sel_s[wave][lane] = first;
    __syncthreads();

    // ---- gather X = [rel_xyz(3) | features(32)] into LDS ------------------
    {
        int s = lane >> 1, h = lane & 1;
        int row = sel_s[wave][s];
        float* X = &bufA[wave][0];
        const float* fr = bfp + (size_t)row * NC + h * 16;
#pragma unroll
        for (int q = 0; q < 4; ++q) {
            float4 v = *(const float4*)(fr + q * 4);
            int base = s * XS + 3 + h * 16 + q * 4;
            X[base + 0] = v.x; X[base + 1] = v.y;
            X[base + 2] = v.z; X[base + 3] = v.w;
        }
        if (h == 0) {
            X[s * XS + 0] = __fsub_rn(bxp[row * 3 + 0], cx);
            X[s * XS + 1] = __fsub_rn(bxp[row * 3 + 1], cy);
            X[s * XS + 2] = __fsub_rn(bxp[row * 3 + 2], cz);
        }
    }
    __syncthreads();

    const int sg = lane >> 3;   // sample group: samples sg*4 .. sg*4+3
    const int og = lane & 7;    // output-channel group

    // ---- layer 1: 35 -> 64 (8 outs = 4 f32x2 pairs) -----------------------
    {
        f32x2 acc[4][4];
#pragma unroll
        for (int j = 0; j < 4; ++j)
#pragma unroll
            for (int q = 0; q < 4; ++q) acc[j][q] = (f32x2)0.f;
        const float* X = &bufA[wave][0];
        for (int c = 0; c < 35; ++c) {
            float xv[4];
#pragma unroll
            for (int j = 0; j < 4; ++j) xv[j] = X[(sg * 4 + j) * XS + c];
            const float* wr = w1 + c * 64 + og * 8;
            float4 wa = *(const float4*)(wr);
            float4 wb = *(const float4*)(wr + 4);
            f32x2 wp[4] = {{wa.x, wa.y}, {wa.z, wa.w}, {wb.x, wb.y}, {wb.z, wb.w}};
#pragma unroll
            for (int j = 0; j < 4; ++j) {
                f32x2 xx; xx.x = xv[j]; xx.y = xv[j];
#pragma unroll
                for (int q = 0; q < 4; ++q) pk_fma(acc[j][q], xx, wp[q]);
            }
        }
        float4 ba = *(const float4*)(b1 + og * 8);
        float4 bb = *(const float4*)(b1 + og * 8 + 4);
        float bias[8] = {ba.x, ba.y, ba.z, ba.w, bb.x, bb.y, bb.z, bb.w};
        float* H = &bufB[wave][0];
#pragma unroll
        for (int j = 0; j < 4; ++j)
#pragma unroll
            for (int q = 0; q < 4; ++q) {
                H[(sg * 4 + j) * HS + og * 8 + 2 * q]     = fmaxf(acc[j][q].x + bias[2 * q], 0.f);
                H[(sg * 4 + j) * HS + og * 8 + 2 * q + 1] = fmaxf(acc[j][q].y + bias[2 * q + 1], 0.f);
            }
    }
    __syncthreads();

    // ---- layer 2: 64 -> 64 ------------------------------------------------
    {
        f32x2 acc[4][4];
#pragma unroll
        for (int j = 0; j < 4; ++j)
#pragma unroll
            for (int q = 0; q < 4; ++q) acc[j][q] = (f32x2)0.f;
        const float* H = &bufB[wave][0];
        for (int c = 0; c < 64; ++c) {
            float xv[4];
#pragma unroll
            for (int j = 0; j < 4; ++j) xv[j] = H[(sg * 4 + j) * HS + c];
            const float* wr = w2 + c * 64 + og * 8;
            float4 wa = *(const float4*)(wr);
            float4 wb = *(const float4*)(wr + 4);
            f32x2 wp[4] = {{wa.x, wa.y}, {wa.z, wa.w}, {wb.x, wb.y}, {wb.z, wb.w}};
#pragma unroll
            for (int j = 0; j < 4; ++j) {
                f32x2 xx; xx.x = xv[j]; xx.y = xv[j];
#pragma unroll
                for (int q = 0; q < 4; ++q) pk_fma(acc[j][q], xx, wp[q]);
            }
        }
        float4 ba = *(const float4*)(b2 + og * 8);
        float4 bb = *(const float4*)(b2 + og * 8 + 4);
        float bias[8] = {ba.x, ba.y, ba.z, ba.w, bb.x, bb.y, bb.z, bb.w};
        float* H2 = &bufA[wave][0];
#pragma unroll
        for (int j = 0; j < 4; ++j)
#pragma unroll
            for (int q = 0; q < 4; ++q) {
                H2[(sg * 4 + j) * HS + og * 8 + 2 * q]     = fmaxf(acc[j][q].x + bias[2 * q], 0.f);
                H2[(sg * 4 + j) * HS + og * 8 + 2 * q + 1] = fmaxf(acc[j][q].y + bias[2 * q + 1], 0.f);
            }
    }
    __syncthreads();

    // ---- layer 3: 64 -> 128 (16 outs = 8 pairs), maxpool over 32 ----------
    {
        f32x2 acc[4][8];
#pragma unroll
        for (int j = 0; j < 4; ++j)
#pragma unroll
            for (int q = 0; q < 8; ++q) acc[j][q] = (f32x2)0.f;
        const float* H = &bufA[wave][0];
        for (int c = 0; c < 64; ++c) {
            float xv[4];
#pragma unroll
            for (int j = 0; j < 4; ++j) xv[j] = H[(sg * 4 + j) * HS + c];
            const float* wr = w3 + c * 128 + og * 16;
            float4 wq[4];
#pragma unroll
            for (int q = 0; q < 4; ++q) wq[q] = *(const float4*)(wr + q * 4);
            f32x2 wp[8] = {{wq[0].x, wq[0].y}, {wq[0].z, wq[0].w},
                           {wq[1].x, wq[1].y}, {wq[1].z, wq[1].w},
                           {wq[2].x, wq[2].y}, {wq[2].z, wq[2].w},
                           {wq[3].x, wq[3].y}, {wq[3].z, wq[3].w}};
#pragma unroll
            for (int j = 0; j < 4; ++j) {
                f32x2 xx; xx.x = xv[j]; xx.y = xv[j];
#pragma unroll
                for (int q = 0; q < 8; ++q) pk_fma(acc[j][q], xx, wp[q]);
            }
        }
        // maxpool over 4 local samples, then across sg via shuffles
        float m[16];
#pragma unroll
        for (int q = 0; q < 8; ++q) {
            float t0x = fmaxf(acc[0][q].x, acc[1][q].x);
            float t1x = fmaxf(acc[2][q].x, acc[3][q].x);
            float t0y = fmaxf(acc[0][q].y, acc[1][q].y);
            float t1y = fmaxf(acc[2][q].y, acc[3][q].y);
            m[2 * q]     = fmaxf(t0x, t1x);
            m[2 * q + 1] = fmaxf(t0y, t1y);
        }
#pragma unroll
        for (int off = 8; off <= 32; off <<= 1)
#pragma unroll
            for (int o = 0; o < 16; ++o) m[o] = fmaxf(m[o], __shfl_xor(m[o], off));
        if (sg == 0) {
            float4 bq[4];
#pragma unroll
            for (int q = 0; q < 4; ++q) bq[q] = *(const float4*)(b3 + og * 16 + q * 4);
            float bias[16] = {bq[0].x, bq[0].y, bq[0].z, bq[0].w,
                              bq[1].x, bq[1].y, bq[1].z, bq[1].w,
                              bq[2].x, bq[2].y, bq[2].z, bq[2].w,
                              bq[3].x, bq[3].y, bq[3].z, bq[3].w};
#pragma unroll
            for (int o = 0; o < 16; ++o) {
                float v = fmaxf(m[o] + bias[o], 0.f);
                out_feat[((size_t)b * 128 + og * 16 + o) * NPOINT + p] = v;
            }
        }
    }
}

// ---------------------------------------------------------------------------
extern "C" void kernel_launch(void* const* d_in, const int* in_sizes, int n_in,
                              void* d_out, int out_size, void* d_ws, size_t ws_size,
                              hipStream_t stream) {
    const float* xyz      = (const float*)d_in[0];
    const float* normal   = (const float*)d_in[1];
    const float* features = (const float*)d_in[2];
    const float* w1 = (const float*)d_in[3];
    const float* b1 = (const float*)d_in[4];
    const float* w2 = (const float*)d_in[5];
    const float* b2 = (const float*)d_in[6];
    const float* w3 = (const float*)d_in[7];
    const float* b3 = (const float*)d_in[8];

    float* out        = (float*)d_out;
    float* out_xyz    = out;                       // (8,1024,3)
    float* out_normal = out + NB * NPOINT * 3;     // (8,1024,3)
    float* out_feat   = out + 2 * NB * NPOINT * 3; // (8,128,1024)

    const int dyn_lds = NN * 3 * sizeof(float);    // 96 KB coords
    // Allow >64 KB dynamic LDS (idempotent; not a stream op, capture-safe).
    (void)hipFuncSetAttribute((const void*)fps_kernel,
                              hipFuncAttributeMaxDynamicSharedMemorySize,
                              dyn_lds);

    hipLaunchKernelGGL(fps_kernel, dim3(NB), dim3(FPS_T), dyn_lds, stream,
                       xyz, normal, out_xyz, out_normal);
    hipLaunchKernelGGL(group_mlp_kernel, dim3(NB * NPOINT / K2_WAVES),
                       dim3(64 * K2_WAVES), 0, stream,
                       xyz, features, w1, b1, w2, b2, w3, b3, out_xyz, out_feat);
}